// Round 15
// baseline (2537.906 us; speedup 1.0000x reference)
//
#include <hip/hip_runtime.h>

// ---------------- problem constants ----------------
#define T_STEPS 128
#define N_B     512
#define D_IN    1024
#define H_DIM   1024
#define G_DIM   3072        // 3*H
#define M_ALL   (T_STEPS * N_B)   // 65536 rows
#define BAR_STRIDE 64       // 256B per barrier counter

typedef short          s8v  __attribute__((ext_vector_type(8)));   // 8 bf16 (4 VGPR)
typedef float          f4v  __attribute__((ext_vector_type(4)));
typedef unsigned short u4v  __attribute__((ext_vector_type(4)));

__device__ __forceinline__ unsigned short f2bf(float f) {
  union { float f; unsigned u; } v; v.f = f;
  unsigned r = v.u + 0x7FFFu + ((v.u >> 16) & 1u);   // RNE
  return (unsigned short)(r >> 16);
}
__device__ __forceinline__ float bf2f(unsigned short h) {
  union { unsigned u; float f; } v; v.u = ((unsigned)h) << 16;
  return v.f;
}
__device__ __forceinline__ void async16(const void* g, void* l) {
  __builtin_amdgcn_global_load_lds(
      (const __attribute__((address_space(1))) unsigned*)g,
      (__attribute__((address_space(3))) unsigned*)l, 16, 0, 0);
}
// sc0|sc1: bypass stale L1/L2, read from the shared Infinity Cache (cross-XCD h)
__device__ __forceinline__ void async16_coh(const void* g, void* l) {
  __builtin_amdgcn_global_load_lds(
      (const __attribute__((address_space(1))) unsigned*)g,
      (__attribute__((address_space(3))) unsigned*)l, 16, 0, 17);
}
// sc0|sc1 coherent bf16 store: write through to the coherence point (cross-XCD h)
__device__ __forceinline__ void store_bf16_coh(unsigned short* p, unsigned short v) {
  unsigned v32 = v;
  asm volatile("global_store_short %0, %1, off sc0 sc1" :: "v"(p), "v"(v32) : "memory");
}
__device__ __forceinline__ float sigmoidf_(float x) { return 1.f / (1.f + __expf(-x)); }
__device__ __forceinline__ float tanhf_(float x)    { return 1.f - 2.f / (1.f + __expf(2.f * x)); }

// ---------------- f32 -> bf16 conversion (vectorized, grid-stride) ----------------
__global__ void cvt_bf16(const float* __restrict__ in, unsigned short* __restrict__ out, long n4) {
  long i = (long)blockIdx.x * blockDim.x + threadIdx.x;
  long stride = (long)gridDim.x * blockDim.x;
  for (; i < n4; i += stride) {
    f4v v = *(const f4v*)(in + i * 4);
    u4v o;
    #pragma unroll
    for (int e = 0; e < 4; ++e) o[e] = f2bf(v[e]);
    *(u4v*)(out + i * 4) = o;
  }
}

// ---------------- reset[t] = (t==0) || any(m[t,:]==1.0) ----------------
__global__ void reset_kernel(const float* __restrict__ masks, int* __restrict__ reset) {
  const int t = blockIdx.x;
  __shared__ int flag;
  if (threadIdx.x == 0) flag = (t == 0) ? 1 : 0;
  __syncthreads();
  if (t > 0 && masks[(size_t)t * N_B + threadIdx.x] == 1.0f) flag = 1;  // benign same-value race
  __syncthreads();
  if (threadIdx.x == 0) reset[t] = flag;
}

// ---------------- xp GEMM v2: 256x128 tile, 3-buffer counted-vmcnt pipeline (T3/T4) ----------------
// C^T[g][m] = sum_k A[m][k]*B[g][k] + bias[g].  A: x bf16 [65536][1024], B: W_ih [3072][1024].
// 512 thr = 8 waves (2M x 4N), per-wave output 128x32, BK=64, LDS 144KB (3 bufs A 32KB + B 16KB).
// Schedule per K-tile: vmcnt(12) [2 K-tiles in flight] -> s_barrier -> 32 MFMA/wave ->
// s_barrier -> stage(kt+3 into buf kt%3). vmcnt never 0 in steady state (tail 12/6/0).
// Race audit: per-wave vmcnt before bar1 => ALL waves' slab portions arrived; stage issued
// after bar2 => all waves done reading the buffer being overwritten.
// XCD-panel mapping: the 24 N-blocks sharing an A row-panel land on one XCD (A fetched ~once).
__global__ __launch_bounds__(512, 1) void gemm_xp2(const unsigned short* __restrict__ A,
                                                   const unsigned short* __restrict__ B,
                                                   const float* __restrict__ bias,
                                                   unsigned short* __restrict__ C) {
  const int p = blockIdx.x;
  const int xcd = p & 7, r = p >> 3;          // r in 0..767
  const int by = xcd * 32 + r / 24;           // 0..255 (M panel), co-XCD for shared panel
  const int bx = r % 24;                      // 0..23  (N tile)
  const int m0 = by * 256, n0 = bx * 128;
  const int tid = threadIdx.x, wid = tid >> 6, l = tid & 63;
  const int l15 = l & 15, l4 = l >> 4;
  const int wm = wid >> 2, wn = wid & 3;      // wave -> (M-half of 128, N-quarter of 32)

  __shared__ unsigned short As[3][256 * 64];  // 96 KB
  __shared__ unsigned short Bs[3][128 * 64];  // 48 KB

  const int srow = l >> 3;                    // row within 8-row staging segment
  const int selem = ((l & 7) ^ srow) * 8;     // pre-swizzled source col (elements)
  const int swz_rd = (l15 & 7) << 4;          // read-side row-XOR

  f4v zero4 = {0.f, 0.f, 0.f, 0.f};
  f4v acc[8][2];
  #pragma unroll
  for (int i = 0; i < 8; ++i)
    #pragma unroll
    for (int j = 0; j < 2; ++j) acc[i][j] = zero4;

  // stage one K-tile (BK=64): A 4 instr/wave (32 rows), B 2 instr/wave (16 rows)
  auto stage = [&](int buf, int kt) {
    #pragma unroll
    for (int c = 0; c < 4; ++c) {
      int s = wid * 4 + c;                    // 0..31 segments of 8 rows
      int row = s * 8 + srow;                 // 0..255
      async16(A + (size_t)(m0 + row) * 1024 + kt * 64 + selem, &As[buf][s * 512]);
    }
    #pragma unroll
    for (int c = 0; c < 2; ++c) {
      int s = wid * 2 + c;                    // 0..15 segments of 8 rows
      int row = s * 8 + srow;                 // 0..127
      async16(B + (size_t)(n0 + row) * 1024 + kt * 64 + selem, &Bs[buf][s * 512]);
    }
  };

  stage(0, 0); stage(1, 1); stage(2, 2);      // prologue: 3 K-tiles in flight (18 loads/wave)

  for (int kt = 0; kt < 16; ++kt) {
    if (kt < 14)       asm volatile("s_waitcnt vmcnt(12)" ::: "memory");  // kt's slab arrived
    else if (kt == 14) asm volatile("s_waitcnt vmcnt(6)"  ::: "memory");
    else               asm volatile("s_waitcnt vmcnt(0)"  ::: "memory");
    __builtin_amdgcn_s_barrier();             // all waves' portions arrived
    __builtin_amdgcn_sched_barrier(0);
    const int buf = kt % 3;
    const char* ab = (const char*)&As[buf][0];
    const char* bb = (const char*)&Bs[buf][0];
    __builtin_amdgcn_s_setprio(1);
    #pragma unroll
    for (int ks = 0; ks < 2; ++ks) {
      const int kbb = (ks * 64 + l4 * 16) ^ swz_rd;
      s8v a[8], b[2];
      #pragma unroll
      for (int i = 0; i < 8; ++i)
        a[i] = *(const s8v*)(ab + (wm * 128 + i * 16 + l15) * 128 + kbb);
      #pragma unroll
      for (int j = 0; j < 2; ++j)
        b[j] = *(const s8v*)(bb + (wn * 32 + j * 16 + l15) * 128 + kbb);
      #pragma unroll
      for (int i = 0; i < 8; ++i)
        #pragma unroll
        for (int j = 0; j < 2; ++j)
          acc[i][j] = __builtin_amdgcn_mfma_f32_16x16x32_bf16(a[i], b[j], acc[i][j], 0, 0, 0);
    }
    __builtin_amdgcn_s_setprio(0);
    __builtin_amdgcn_s_barrier();             // all waves done reading buf
    __builtin_amdgcn_sched_barrier(0);
    if (kt + 3 < 16) stage(buf, kt + 3);      // overwrite now-free buffer; 2 iters of lead
  }

  // epilogue: +bias, transposed 8B vector stores into xpT[g][m]
  #pragma unroll
  for (int j = 0; j < 2; ++j) {
    int gcol = n0 + wn * 32 + j * 16 + l15;
    float bv = bias[gcol];
    #pragma unroll
    for (int i = 0; i < 8; ++i) {
      int mrow = m0 + wm * 128 + i * 16 + l4 * 4;
      u4v o;
      #pragma unroll
      for (int rr = 0; rr < 4; ++rr) o[rr] = f2bf(acc[i][j][rr] + bv);
      *(u4v*)(C + (size_t)gcol * M_ALL + mrow) = o;
    }
  }
}

// ---------------- persistent GRU, v8 (unchanged from R14, measured 1681us) ----------------
__global__ __launch_bounds__(256, 1) void rnn_all(
    const unsigned short* __restrict__ Whh,   // [3072][1024] bf16
    const unsigned short* __restrict__ xpT,   // [3072][65536] bf16 (+b_ih), transposed
    const float* __restrict__ masks,          // [T*N]
    const int* __restrict__ reset,            // [T]
    const float* __restrict__ bhh,            // [3072]
    const float* __restrict__ hxs,            // [512][1024] initial h (f32)
    unsigned short* hbuf,                     // [2][512][1024] bf16 state
    float* __restrict__ y,                    // [T*N][1024] (d_out)
    float* __restrict__ hlast,                // [512][1024]  (d_out tail)
    unsigned* bar) {                          // [8*BAR_STRIDE] padded nt-group counters
  const int bid = blockIdx.x;
  const int jt = bid & 31, nt = bid >> 5;
  const int j0 = jt * 32, n0 = nt * 64;
  const int tid = threadIdx.x, w = tid >> 6, l = tid & 63;
  const int l15 = l & 15, l4 = l >> 4;
  const int wn = w & 1, wj = w >> 1;          // wave -> (n-half of 32, j-half of 16)
  const size_t NH = (size_t)N_B * H_DIM;

  __shared__ unsigned short Hs[3][64 * 128];  // 48 KB (h slab, swizzled)
  __shared__ unsigned short Ws[3][96 * 128];  // 72 KB (W slab, swizzled)
  __shared__ unsigned short xpl[3][32][64];   // 12 KB xp gate operands (swizzled cols)

  const int lrow4 = l >> 4;                   // staging: lane -> row-within-4
  const int lcb = (l & 15) * 16;              // staging: lane -> 16B col slot
  const int swz_rd = (l15 & 7) << 4;          // read-side row-XOR

  const int jj = j0 + wj * 16 + l15;
  const float br = bhh[jj];
  const float bz = bhh[H_DIM + jj];
  const float bn = bhh[2 * H_DIM + jj];

  // h_prev f32 in registers, carried across ALL 128 steps
  float hreg[2][4];
  #pragma unroll
  for (int i = 0; i < 2; ++i)
    #pragma unroll
    for (int r = 0; r < 4; ++r)
      hreg[i][r] = hxs[(size_t)(n0 + wn * 32 + i * 16 + l4 * 4 + r) * H_DIM + jj];

  f4v zero4 = {0.f, 0.f, 0.f, 0.f};
  s8v zer8 = {0, 0, 0, 0, 0, 0, 0, 0};

  auto stageH = [&](const unsigned short* hread, int buf, int kt) {  // 4 VMEM/wave
    #pragma unroll
    for (int q = 0; q < 4; ++q) {
      int rb = w * 16 + q * 4;
      int row = rb + lrow4;                                   // 0..63
      int cb = lcb ^ ((row & 7) << 4);                        // byte in 256B row
      async16_coh(hread + (size_t)(n0 + row) * H_DIM + kt * 128 + (cb >> 1),
                  &Hs[buf][rb * 128]);
    }
  };
  auto stageW = [&](int buf, int kt) {                        // 6 VMEM/wave
    #pragma unroll
    for (int q = 0; q < 6; ++q) {
      int rb = w * 24 + q * 4;
      int row = rb + lrow4;                                   // 0..95
      int gate = row >> 5, jjl = row & 31;
      int cb = lcb ^ ((row & 7) << 4);
      async16(Whh + ((size_t)gate * H_DIM + j0 + jjl) * H_DIM + kt * 128 + (cb >> 1),
              &Ws[buf][rb * 128]);
    }
  };
  auto stageXP = [&](int t) {                                 // 3 VMEM/wave
    const int jl = w * 8 + (l >> 3);
    const int nelem = ((l & 7) ^ (l >> 3)) * 8;               // pre-swizzled n-offset
    #pragma unroll
    for (int g3 = 0; g3 < 3; ++g3)
      async16(xpT + (size_t)(g3 * H_DIM + j0 + jl) * M_ALL + (size_t)t * N_B + n0 + nelem,
              &xpl[g3][w * 8][0]);
  };

  // ---- priming for t=0 ----
  int rst = reset[0];
  bool zo[2];
  float mreg[2][4];
  #pragma unroll
  for (int i = 0; i < 2; ++i) {
    float mv = masks[(size_t)0 * N_B + n0 + wn * 32 + i * 16 + l15];
    zo[i] = rst && (mv == 0.0f);
  }
  #pragma unroll
  for (int i = 0; i < 2; ++i)
    #pragma unroll
    for (int r = 0; r < 4; ++r)
      mreg[i][r] = masks[(size_t)0 * N_B + n0 + wn * 32 + i * 16 + l4 * 4 + r];
  stageW(0, 0); stageW(1, 1); stageW(2, 2);
  stageXP(0);

  for (int t = 0; t < T_STEPS; ++t) {
    const unsigned short* hread = hbuf + (size_t)(t & 1) * NH;
    unsigned short* hwrite = hbuf + (size_t)((t & 1) ^ 1) * NH;

    stageH(hread, 0, 0); stageH(hread, 1, 1); stageH(hread, 2, 2);

    f4v acc[2][3];
    #pragma unroll
    for (int i = 0; i < 2; ++i)
      #pragma unroll
      for (int g3 = 0; g3 < 3; ++g3) acc[i][g3] = zero4;

#define KT_BODY(KT, VM, DO_STAGE)                                              \
    {                                                                          \
      asm volatile("s_waitcnt vmcnt(" #VM ")" ::: "memory");                   \
      __builtin_amdgcn_s_barrier();                                            \
      __builtin_amdgcn_sched_barrier(0);                                       \
      if (DO_STAGE) { stageH(hread, (KT + 2) % 3, KT + 2); stageW((KT + 2) % 3, KT + 2); } \
      const char* hb = (const char*)&Hs[KT % 3][0];                            \
      const char* wb = (const char*)&Ws[KT % 3][0];                            \
      _Pragma("unroll")                                                        \
      for (int ks = 0; ks < 4; ++ks) {                                         \
        const int kbb = (ks * 64 + l4 * 16) ^ swz_rd;                          \
        s8v a[2], b[3];                                                        \
        _Pragma("unroll")                                                      \
        for (int i = 0; i < 2; ++i) {                                          \
          a[i] = *(const s8v*)(hb + (wn * 32 + i * 16 + l15) * 256 + kbb);     \
          if (zo[i]) a[i] = zer8;                                              \
        }                                                                      \
        _Pragma("unroll")                                                      \
        for (int g3 = 0; g3 < 3; ++g3)                                         \
          b[g3] = *(const s8v*)(wb + (g3 * 32 + wj * 16 + l15) * 256 + kbb);   \
        _Pragma("unroll")                                                      \
        for (int i = 0; i < 2; ++i)                                            \
          _Pragma("unroll")                                                    \
          for (int g3 = 0; g3 < 3; ++g3)                                       \
            acc[i][g3] = __builtin_amdgcn_mfma_f32_16x16x32_bf16(a[i], b[g3],  \
                                                                acc[i][g3], 0, 0, 0); \
      }                                                                        \
    }

    KT_BODY(0, 8,  false)
    KT_BODY(1, 4,  true)
    KT_BODY(2, 10, true)
    KT_BODY(3, 10, true)
    KT_BODY(4, 10, true)
    KT_BODY(5, 10, true)
    KT_BODY(6, 10, false)
    KT_BODY(7, 0,  false)
#undef KT_BODY

    #pragma unroll
    for (int i = 0; i < 2; ++i) {
      #pragma unroll
      for (int r = 0; r < 4; ++r) {
        const int n = n0 + wn * 32 + i * 16 + l4 * 4 + r;
        const int nl = wn * 32 + i * 16 + l4 * 4 + r;           // n-local 0..63
        const int jl = wj * 16 + l15;                           // j-local 0..31
        float hprev = hreg[i][r];
        if (rst && mreg[i][r] == 0.0f) hprev = 0.0f;
        const float hr = acc[i][0][r] + br;
        const float hz = acc[i][1][r] + bz;
        const float hn = acc[i][2][r] + bn;
        const char* xb = (const char*)&xpl[0][0][0];
        const int nb = (nl * 2) ^ ((jl & 7) << 4);              // swizzled byte in 128B col
        const float xr = bf2f(*(const unsigned short*)(xb + 0 * 4096 + jl * 128 + nb));
        const float xz = bf2f(*(const unsigned short*)(xb + 1 * 4096 + jl * 128 + nb));
        const float xn = bf2f(*(const unsigned short*)(xb + 2 * 4096 + jl * 128 + nb));
        const float rg = sigmoidf_(xr + hr);
        const float zg = sigmoidf_(xz + hz);
        const float ng = tanhf_(xn + rg * hn);
        const float hnew = (1.f - zg) * ng + zg * hprev;
        hreg[i][r] = hnew;
        const size_t gidx = (size_t)n * H_DIM + jj;
        y[(size_t)t * NH + gidx] = hnew;
        store_bf16_coh(hwrite + gidx, f2bf(hnew));
        if (t == T_STEPS - 1) hlast[gidx] = hnew;
      }
    }

    __syncthreads();                            // drains vmcnt(0): h stores visible

    int rstN = 0;
    bool zoN[2] = {false, false};
    float mregN[2][4];
    if (t + 1 < T_STEPS) {
      rstN = reset[t + 1];
      #pragma unroll
      for (int i = 0; i < 2; ++i) {
        float mv = masks[(size_t)(t + 1) * N_B + n0 + wn * 32 + i * 16 + l15];
        zoN[i] = rstN && (mv == 0.0f);
      }
      #pragma unroll
      for (int i = 0; i < 2; ++i)
        #pragma unroll
        for (int r = 0; r < 4; ++r)
          mregN[i][r] = masks[(size_t)(t + 1) * N_B + n0 + wn * 32 + i * 16 + l4 * 4 + r];
      stageW(0, 0); stageW(1, 1); stageW(2, 2);
      stageXP(t + 1);
    }

    if (tid == 0) {
      __hip_atomic_fetch_add(&bar[nt * BAR_STRIDE], 1u, __ATOMIC_RELAXED, __HIP_MEMORY_SCOPE_AGENT);
      const unsigned tgt = 32u * (unsigned)(t + 1);
      while (__hip_atomic_load(&bar[nt * BAR_STRIDE], __ATOMIC_RELAXED, __HIP_MEMORY_SCOPE_AGENT) < tgt)
        __builtin_amdgcn_s_sleep(1);
    }
    __builtin_amdgcn_s_barrier();
    __builtin_amdgcn_sched_barrier(0);

    rst = rstN;
    #pragma unroll
    for (int i = 0; i < 2; ++i) {
      zo[i] = zoN[i];
      #pragma unroll
      for (int r = 0; r < 4; ++r) mreg[i][r] = mregN[i][r];
    }
  }
}

// ---------------- final LayerNorm over y rows (in place) ----------------
__global__ __launch_bounds__(256) void ln_kernel(float* __restrict__ y,
                                                 const float* __restrict__ gamma,
                                                 const float* __restrict__ beta) {
  const size_t row = blockIdx.x;
  float* p = y + row * (size_t)H_DIM;
  const int tid = threadIdx.x;
  f4v v = *(const f4v*)(p + tid * 4);
  float s = v[0] + v[1] + v[2] + v[3];
  float q = v[0] * v[0] + v[1] * v[1] + v[2] * v[2] + v[3] * v[3];
  #pragma unroll
  for (int off = 32; off > 0; off >>= 1) {
    s += __shfl_down(s, off);
    q += __shfl_down(q, off);
  }
  __shared__ float sb[8];
  const int wid = tid >> 6, lid = tid & 63;
  if (lid == 0) { sb[wid] = s; sb[4 + wid] = q; }
  __syncthreads();
  float S = sb[0] + sb[1] + sb[2] + sb[3];
  float Q = sb[4] + sb[5] + sb[6] + sb[7];
  float mean = S * (1.f / H_DIM);
  float var = Q * (1.f / H_DIM) - mean * mean;
  float inv = rsqrtf(var + 1e-5f);
  f4v g4 = *(const f4v*)(gamma + tid * 4);
  f4v b4 = *(const f4v*)(beta + tid * 4);
  f4v o;
  #pragma unroll
  for (int e = 0; e < 4; ++e) o[e] = (v[e] - mean) * inv * g4[e] + b4[e];
  *(f4v*)(p + tid * 4) = o;
}

// ---------------- host ----------------
extern "C" void kernel_launch(void* const* d_in, const int* in_sizes, int n_in,
                              void* d_out, int out_size, void* d_ws, size_t ws_size,
                              hipStream_t stream) {
  const float* x     = (const float*)d_in[0];
  const float* hxs   = (const float*)d_in[1];
  const float* masks = (const float*)d_in[2];
  const float* W_ih  = (const float*)d_in[3];
  const float* W_hh  = (const float*)d_in[4];
  const float* b_ih  = (const float*)d_in[5];
  const float* b_hh  = (const float*)d_in[6];
  const float* gamma = (const float*)d_in[7];
  const float* beta  = (const float*)d_in[8];
  float* y = (float*)d_out;                                 // [65536][1024]
  float* hlast = y + (size_t)T_STEPS * N_B * H_DIM;         // [512][1024]

  char* ws = (char*)d_ws;
  unsigned short* Wih_bf = (unsigned short*)ws;  ws += (size_t)G_DIM * D_IN * 2;       // 6.3 MB
  unsigned short* Whh_bf = (unsigned short*)ws;  ws += (size_t)G_DIM * H_DIM * 2;      // 6.3 MB
  unsigned short* xc_bf  = (unsigned short*)ws;  ws += (size_t)M_ALL * D_IN * 2;       // 134 MB
  unsigned short* xpT_bf = (unsigned short*)ws;  ws += (size_t)G_DIM * M_ALL * 2;      // 403 MB
  unsigned short* hbuf   = (unsigned short*)ws;  ws += (size_t)2 * N_B * H_DIM * 2;    // 2.1 MB
  unsigned* bars         = (unsigned*)ws;        ws += 8 * BAR_STRIDE * sizeof(unsigned);
  int* reset             = (int*)ws;             ws += 512;

  hipMemsetAsync(bars, 0, 8 * BAR_STRIDE * sizeof(unsigned), stream);
  cvt_bf16<<<1024, 256, 0, stream>>>(W_ih, Wih_bf, (long)G_DIM * D_IN / 4);
  cvt_bf16<<<1024, 256, 0, stream>>>(W_hh, Whh_bf, (long)G_DIM * H_DIM / 4);
  cvt_bf16<<<512, 256, 0, stream>>>(hxs, hbuf, (long)N_B * H_DIM / 4);   // hbuf[0] = bf16(h0)
  reset_kernel<<<128, 512, 0, stream>>>(masks, reset);
  cvt_bf16<<<4096, 256, 0, stream>>>(x, xc_bf, (long)M_ALL * D_IN / 4);

  gemm_xp2<<<6144, 512, 0, stream>>>(xc_bf, Wih_bf, b_ih, xpT_bf);   // (24 N x 256 M tiles)

  rnn_all<<<256, 256, 0, stream>>>(Whh_bf, xpT_bf, masks, reset, b_hh,
                                   hxs, hbuf, y, hlast, bars);

  ln_kernel<<<T_STEPS * N_B, 256, 0, stream>>>(y, gamma, beta);
}

// Round 16
// 2268.900 us; speedup vs baseline: 1.1186x; 1.1186x over previous
//
#include <hip/hip_runtime.h>

// ---------------- problem constants ----------------
#define T_STEPS 128
#define N_B     512
#define D_IN    1024
#define H_DIM   1024
#define G_DIM   3072        // 3*H
#define M_ALL   (T_STEPS * N_B)   // 65536 rows
#define BAR_STRIDE 64       // 256B per barrier counter

typedef short          s8v  __attribute__((ext_vector_type(8)));   // 8 bf16 (4 VGPR)
typedef float          f4v  __attribute__((ext_vector_type(4)));
typedef unsigned short u4v  __attribute__((ext_vector_type(4)));

__device__ __forceinline__ unsigned short f2bf(float f) {
  union { float f; unsigned u; } v; v.f = f;
  unsigned r = v.u + 0x7FFFu + ((v.u >> 16) & 1u);   // RNE
  return (unsigned short)(r >> 16);
}
__device__ __forceinline__ float bf2f(unsigned short h) {
  union { unsigned u; float f; } v; v.u = ((unsigned)h) << 16;
  return v.f;
}
__device__ __forceinline__ void async16(const void* g, void* l) {
  __builtin_amdgcn_global_load_lds(
      (const __attribute__((address_space(1))) unsigned*)g,
      (__attribute__((address_space(3))) unsigned*)l, 16, 0, 0);
}
// sc0|sc1: bypass stale L1/L2, read from the shared Infinity Cache (cross-XCD h)
__device__ __forceinline__ void async16_coh(const void* g, void* l) {
  __builtin_amdgcn_global_load_lds(
      (const __attribute__((address_space(1))) unsigned*)g,
      (__attribute__((address_space(3))) unsigned*)l, 16, 0, 17);
}
// sc0|sc1 coherent bf16 store: write through to the coherence point (cross-XCD h)
__device__ __forceinline__ void store_bf16_coh(unsigned short* p, unsigned short v) {
  unsigned v32 = v;
  asm volatile("global_store_short %0, %1, off sc0 sc1" :: "v"(p), "v"(v32) : "memory");
}
__device__ __forceinline__ float sigmoidf_(float x) { return 1.f / (1.f + __expf(-x)); }
__device__ __forceinline__ float tanhf_(float x)    { return 1.f - 2.f / (1.f + __expf(2.f * x)); }

// ---------------- f32 -> bf16 conversion (vectorized, grid-stride) ----------------
__global__ void cvt_bf16(const float* __restrict__ in, unsigned short* __restrict__ out, long n4) {
  long i = (long)blockIdx.x * blockDim.x + threadIdx.x;
  long stride = (long)gridDim.x * blockDim.x;
  for (; i < n4; i += stride) {
    f4v v = *(const f4v*)(in + i * 4);
    u4v o;
    #pragma unroll
    for (int e = 0; e < 4; ++e) o[e] = f2bf(v[e]);
    *(u4v*)(out + i * 4) = o;
  }
}

// ---------------- reset[t] = (t==0) || any(m[t,:]==1.0) ----------------
__global__ void reset_kernel(const float* __restrict__ masks, int* __restrict__ reset) {
  const int t = blockIdx.x;
  __shared__ int flag;
  if (threadIdx.x == 0) flag = (t == 0) ? 1 : 0;
  __syncthreads();
  if (t > 0 && masks[(size_t)t * N_B + threadIdx.x] == 1.0f) flag = 1;  // benign same-value race
  __syncthreads();
  if (threadIdx.x == 0) reset[t] = flag;
}

// ---------------- xp GEMM (ALL timesteps), TRANSPOSED output + LDS swizzle ----------------
// Proven R11/R13/R14: 0 bank conflicts, ~537us, MfmaUtil 35% (2-phase structural ceiling).
__global__ __launch_bounds__(256) void gemm_xp(const unsigned short* __restrict__ A,
                                               const unsigned short* __restrict__ B,
                                               const float* __restrict__ bias,
                                               unsigned short* __restrict__ C) {
  const int m0 = blockIdx.y * 128, g0 = blockIdx.x * 128;
  const int tid = threadIdx.x, wv = tid >> 6, l = tid & 63;
  const int l15 = l & 15, l4 = l >> 4;
  const int wr = wv >> 1, wc = wv & 1;
  __shared__ unsigned short As[128 * 64], Bs[128 * 64];

  f4v zero4 = {0.f, 0.f, 0.f, 0.f};
  f4v acc[4][4];
  #pragma unroll
  for (int i = 0; i < 4; ++i)
    #pragma unroll
    for (int j = 0; j < 4; ++j) acc[i][j] = zero4;

  const int srow = l >> 3;
  const int selem = ((l & 7) ^ srow) * 8;        // pre-swizzled source col (elements)
  const int swz_rd = (l15 & 7) << 4;             // read-side row-XOR

  for (int kt = 0; kt < 1024; kt += 64) {
    #pragma unroll
    for (int cc = 0; cc < 4; ++cc) {
      int s = wv * 4 + cc;
      int row = s * 8 + srow;
      async16(A + (size_t)(m0 + row) * 1024 + kt + selem, &As[s * 512]);
      async16(B + (size_t)(g0 + row) * 1024 + kt + selem, &Bs[s * 512]);
    }
    __syncthreads();
    #pragma unroll
    for (int ks = 0; ks < 2; ++ks) {
      s8v a[4], b[4];
      #pragma unroll
      for (int i = 0; i < 4; ++i) {
        int ra = wr * 64 + i * 16 + l15, rb = wc * 64 + i * 16 + l15;
        int cb = (ks * 64 + l4 * 16) ^ swz_rd;
        a[i] = *(const s8v*)((const char*)As + ra * 128 + cb);
        b[i] = *(const s8v*)((const char*)Bs + rb * 128 + cb);
      }
      #pragma unroll
      for (int i = 0; i < 4; ++i)
        #pragma unroll
        for (int j = 0; j < 4; ++j)
          acc[i][j] = __builtin_amdgcn_mfma_f32_16x16x32_bf16(a[i], b[j], acc[i][j], 0, 0, 0);
    }
    __syncthreads();
  }
  #pragma unroll
  for (int j = 0; j < 4; ++j) {
    int gcol = g0 + wc * 64 + j * 16 + l15;
    float bv = bias[gcol];
    #pragma unroll
    for (int i = 0; i < 4; ++i) {
      int mrow = m0 + wr * 64 + i * 16 + l4 * 4;
      u4v o;
      #pragma unroll
      for (int r = 0; r < 4; ++r) o[r] = f2bf(acc[i][j][r] + bv);
      *(u4v*)(C + (size_t)gcol * M_ALL + mrow) = o;    // transposed, 8B vector store
    }
  }
}

// ---------------- persistent GRU, v8 (R14 config, measured 1652-1681us) ----------------
__global__ __launch_bounds__(256, 1) void rnn_all(
    const unsigned short* __restrict__ Whh,   // [3072][1024] bf16
    const unsigned short* __restrict__ xpT,   // [3072][65536] bf16 (+b_ih), transposed
    const float* __restrict__ masks,          // [T*N]
    const int* __restrict__ reset,            // [T]
    const float* __restrict__ bhh,            // [3072]
    const float* __restrict__ hxs,            // [512][1024] initial h (f32)
    unsigned short* hbuf,                     // [2][512][1024] bf16 state
    float* __restrict__ y,                    // [T*N][1024] (d_out)
    float* __restrict__ hlast,                // [512][1024]  (d_out tail)
    unsigned* bar) {                          // [8*BAR_STRIDE] padded nt-group counters
  const int bid = blockIdx.x;
  const int jt = bid & 31, nt = bid >> 5;
  const int j0 = jt * 32, n0 = nt * 64;
  const int tid = threadIdx.x, w = tid >> 6, l = tid & 63;
  const int l15 = l & 15, l4 = l >> 4;
  const int wn = w & 1, wj = w >> 1;          // wave -> (n-half of 32, j-half of 16)
  const size_t NH = (size_t)N_B * H_DIM;

  __shared__ unsigned short Hs[3][64 * 128];  // 48 KB (h slab, swizzled)
  __shared__ unsigned short Ws[3][96 * 128];  // 72 KB (W slab, swizzled)
  __shared__ unsigned short xpl[3][32][64];   // 12 KB xp gate operands (swizzled cols)

  const int lrow4 = l >> 4;                   // staging: lane -> row-within-4
  const int lcb = (l & 15) * 16;              // staging: lane -> 16B col slot
  const int swz_rd = (l15 & 7) << 4;          // read-side row-XOR

  const int jj = j0 + wj * 16 + l15;
  const float br = bhh[jj];
  const float bz = bhh[H_DIM + jj];
  const float bn = bhh[2 * H_DIM + jj];

  // h_prev f32 in registers, carried across ALL 128 steps
  float hreg[2][4];
  #pragma unroll
  for (int i = 0; i < 2; ++i)
    #pragma unroll
    for (int r = 0; r < 4; ++r)
      hreg[i][r] = hxs[(size_t)(n0 + wn * 32 + i * 16 + l4 * 4 + r) * H_DIM + jj];

  f4v zero4 = {0.f, 0.f, 0.f, 0.f};
  s8v zer8 = {0, 0, 0, 0, 0, 0, 0, 0};

  auto stageH = [&](const unsigned short* hread, int buf, int kt) {  // 4 VMEM/wave
    #pragma unroll
    for (int q = 0; q < 4; ++q) {
      int rb = w * 16 + q * 4;
      int row = rb + lrow4;                                   // 0..63
      int cb = lcb ^ ((row & 7) << 4);                        // byte in 256B row
      async16_coh(hread + (size_t)(n0 + row) * H_DIM + kt * 128 + (cb >> 1),
                  &Hs[buf][rb * 128]);
    }
  };
  auto stageW = [&](int buf, int kt) {                        // 6 VMEM/wave
    #pragma unroll
    for (int q = 0; q < 6; ++q) {
      int rb = w * 24 + q * 4;
      int row = rb + lrow4;                                   // 0..95
      int gate = row >> 5, jjl = row & 31;
      int cb = lcb ^ ((row & 7) << 4);
      async16(Whh + ((size_t)gate * H_DIM + j0 + jjl) * H_DIM + kt * 128 + (cb >> 1),
              &Ws[buf][rb * 128]);
    }
  };
  auto stageXP = [&](int t) {                                 // 3 VMEM/wave
    const int jl = w * 8 + (l >> 3);
    const int nelem = ((l & 7) ^ (l >> 3)) * 8;               // pre-swizzled n-offset
    #pragma unroll
    for (int g3 = 0; g3 < 3; ++g3)
      async16(xpT + (size_t)(g3 * H_DIM + j0 + jl) * M_ALL + (size_t)t * N_B + n0 + nelem,
              &xpl[g3][w * 8][0]);
  };

  // ---- priming for t=0 ----
  int rst = reset[0];
  bool zo[2];
  float mreg[2][4];
  #pragma unroll
  for (int i = 0; i < 2; ++i) {
    float mv = masks[(size_t)0 * N_B + n0 + wn * 32 + i * 16 + l15];
    zo[i] = rst && (mv == 0.0f);
  }
  #pragma unroll
  for (int i = 0; i < 2; ++i)
    #pragma unroll
    for (int r = 0; r < 4; ++r)
      mreg[i][r] = masks[(size_t)0 * N_B + n0 + wn * 32 + i * 16 + l4 * 4 + r];
  stageW(0, 0); stageW(1, 1); stageW(2, 2);
  stageXP(0);

  for (int t = 0; t < T_STEPS; ++t) {
    const unsigned short* hread = hbuf + (size_t)(t & 1) * NH;
    unsigned short* hwrite = hbuf + (size_t)((t & 1) ^ 1) * NH;

    stageH(hread, 0, 0); stageH(hread, 1, 1); stageH(hread, 2, 2);

    f4v acc[2][3];
    #pragma unroll
    for (int i = 0; i < 2; ++i)
      #pragma unroll
      for (int g3 = 0; g3 < 3; ++g3) acc[i][g3] = zero4;

#define KT_BODY(KT, VM, DO_STAGE)                                              \
    {                                                                          \
      asm volatile("s_waitcnt vmcnt(" #VM ")" ::: "memory");                   \
      __builtin_amdgcn_s_barrier();                                            \
      __builtin_amdgcn_sched_barrier(0);                                       \
      if (DO_STAGE) { stageH(hread, (KT + 2) % 3, KT + 2); stageW((KT + 2) % 3, KT + 2); } \
      const char* hb = (const char*)&Hs[KT % 3][0];                            \
      const char* wb = (const char*)&Ws[KT % 3][0];                            \
      _Pragma("unroll")                                                        \
      for (int ks = 0; ks < 4; ++ks) {                                         \
        const int kbb = (ks * 64 + l4 * 16) ^ swz_rd;                          \
        s8v a[2], b[3];                                                        \
        _Pragma("unroll")                                                      \
        for (int i = 0; i < 2; ++i) {                                          \
          a[i] = *(const s8v*)(hb + (wn * 32 + i * 16 + l15) * 256 + kbb);     \
          if (zo[i]) a[i] = zer8;                                              \
        }                                                                      \
        _Pragma("unroll")                                                      \
        for (int g3 = 0; g3 < 3; ++g3)                                         \
          b[g3] = *(const s8v*)(wb + (g3 * 32 + wj * 16 + l15) * 256 + kbb);   \
        _Pragma("unroll")                                                      \
        for (int i = 0; i < 2; ++i)                                            \
          _Pragma("unroll")                                                    \
          for (int g3 = 0; g3 < 3; ++g3)                                       \
            acc[i][g3] = __builtin_amdgcn_mfma_f32_16x16x32_bf16(a[i], b[g3],  \
                                                                acc[i][g3], 0, 0, 0); \
      }                                                                        \
    }

    KT_BODY(0, 8,  false)
    KT_BODY(1, 4,  true)
    KT_BODY(2, 10, true)
    KT_BODY(3, 10, true)
    KT_BODY(4, 10, true)
    KT_BODY(5, 10, true)
    KT_BODY(6, 10, false)
    KT_BODY(7, 0,  false)
#undef KT_BODY

    #pragma unroll
    for (int i = 0; i < 2; ++i) {
      #pragma unroll
      for (int r = 0; r < 4; ++r) {
        const int n = n0 + wn * 32 + i * 16 + l4 * 4 + r;
        const int nl = wn * 32 + i * 16 + l4 * 4 + r;           // n-local 0..63
        const int jl = wj * 16 + l15;                           // j-local 0..31
        float hprev = hreg[i][r];
        if (rst && mreg[i][r] == 0.0f) hprev = 0.0f;
        const float hr = acc[i][0][r] + br;
        const float hz = acc[i][1][r] + bz;
        const float hn = acc[i][2][r] + bn;
        const char* xb = (const char*)&xpl[0][0][0];
        const int nb = (nl * 2) ^ ((jl & 7) << 4);              // swizzled byte in 128B col
        const float xr = bf2f(*(const unsigned short*)(xb + 0 * 4096 + jl * 128 + nb));
        const float xz = bf2f(*(const unsigned short*)(xb + 1 * 4096 + jl * 128 + nb));
        const float xn = bf2f(*(const unsigned short*)(xb + 2 * 4096 + jl * 128 + nb));
        const float rg = sigmoidf_(xr + hr);
        const float zg = sigmoidf_(xz + hz);
        const float ng = tanhf_(xn + rg * hn);
        const float hnew = (1.f - zg) * ng + zg * hprev;
        hreg[i][r] = hnew;
        const size_t gidx = (size_t)n * H_DIM + jj;
        y[(size_t)t * NH + gidx] = hnew;
        store_bf16_coh(hwrite + gidx, f2bf(hnew));
        if (t == T_STEPS - 1) hlast[gidx] = hnew;
      }
    }

    __syncthreads();                            // drains vmcnt(0): h stores visible

    int rstN = 0;
    bool zoN[2] = {false, false};
    float mregN[2][4];
    if (t + 1 < T_STEPS) {
      rstN = reset[t + 1];
      #pragma unroll
      for (int i = 0; i < 2; ++i) {
        float mv = masks[(size_t)(t + 1) * N_B + n0 + wn * 32 + i * 16 + l15];
        zoN[i] = rstN && (mv == 0.0f);
      }
      #pragma unroll
      for (int i = 0; i < 2; ++i)
        #pragma unroll
        for (int r = 0; r < 4; ++r)
          mregN[i][r] = masks[(size_t)(t + 1) * N_B + n0 + wn * 32 + i * 16 + l4 * 4 + r];
      stageW(0, 0); stageW(1, 1); stageW(2, 2);
      stageXP(t + 1);
    }

    if (tid == 0) {
      __hip_atomic_fetch_add(&bar[nt * BAR_STRIDE], 1u, __ATOMIC_RELAXED, __HIP_MEMORY_SCOPE_AGENT);
      const unsigned tgt = 32u * (unsigned)(t + 1);
      while (__hip_atomic_load(&bar[nt * BAR_STRIDE], __ATOMIC_RELAXED, __HIP_MEMORY_SCOPE_AGENT) < tgt)
        __builtin_amdgcn_s_sleep(1);
    }
    __builtin_amdgcn_s_barrier();
    __builtin_amdgcn_sched_barrier(0);

    rst = rstN;
    #pragma unroll
    for (int i = 0; i < 2; ++i) {
      zo[i] = zoN[i];
      #pragma unroll
      for (int r = 0; r < 4; ++r) mreg[i][r] = mregN[i][r];
    }
  }
}

// ---------------- final LayerNorm over y rows (in place) ----------------
__global__ __launch_bounds__(256) void ln_kernel(float* __restrict__ y,
                                                 const float* __restrict__ gamma,
                                                 const float* __restrict__ beta) {
  const size_t row = blockIdx.x;
  float* p = y + row * (size_t)H_DIM;
  const int tid = threadIdx.x;
  f4v v = *(const f4v*)(p + tid * 4);
  float s = v[0] + v[1] + v[2] + v[3];
  float q = v[0] * v[0] + v[1] * v[1] + v[2] * v[2] + v[3] * v[3];
  #pragma unroll
  for (int off = 32; off > 0; off >>= 1) {
    s += __shfl_down(s, off);
    q += __shfl_down(q, off);
  }
  __shared__ float sb[8];
  const int wid = tid >> 6, lid = tid & 63;
  if (lid == 0) { sb[wid] = s; sb[4 + wid] = q; }
  __syncthreads();
  float S = sb[0] + sb[1] + sb[2] + sb[3];
  float Q = sb[4] + sb[5] + sb[6] + sb[7];
  float mean = S * (1.f / H_DIM);
  float var = Q * (1.f / H_DIM) - mean * mean;
  float inv = rsqrtf(var + 1e-5f);
  f4v g4 = *(const f4v*)(gamma + tid * 4);
  f4v b4 = *(const f4v*)(beta + tid * 4);
  f4v o;
  #pragma unroll
  for (int e = 0; e < 4; ++e) o[e] = (v[e] - mean) * inv * g4[e] + b4[e];
  *(f4v*)(p + tid * 4) = o;
}

// ---------------- host ----------------
extern "C" void kernel_launch(void* const* d_in, const int* in_sizes, int n_in,
                              void* d_out, int out_size, void* d_ws, size_t ws_size,
                              hipStream_t stream) {
  const float* x     = (const float*)d_in[0];
  const float* hxs   = (const float*)d_in[1];
  const float* masks = (const float*)d_in[2];
  const float* W_ih  = (const float*)d_in[3];
  const float* W_hh  = (const float*)d_in[4];
  const float* b_ih  = (const float*)d_in[5];
  const float* b_hh  = (const float*)d_in[6];
  const float* gamma = (const float*)d_in[7];
  const float* beta  = (const float*)d_in[8];
  float* y = (float*)d_out;                                 // [65536][1024]
  float* hlast = y + (size_t)T_STEPS * N_B * H_DIM;         // [512][1024]

  char* ws = (char*)d_ws;
  unsigned short* Wih_bf = (unsigned short*)ws;  ws += (size_t)G_DIM * D_IN * 2;       // 6.3 MB
  unsigned short* Whh_bf = (unsigned short*)ws;  ws += (size_t)G_DIM * H_DIM * 2;      // 6.3 MB
  unsigned short* xc_bf  = (unsigned short*)ws;  ws += (size_t)M_ALL * D_IN * 2;       // 134 MB
  unsigned short* xpT_bf = (unsigned short*)ws;  ws += (size_t)G_DIM * M_ALL * 2;      // 403 MB
  unsigned short* hbuf   = (unsigned short*)ws;  ws += (size_t)2 * N_B * H_DIM * 2;    // 2.1 MB
  unsigned* bars         = (unsigned*)ws;        ws += 8 * BAR_STRIDE * sizeof(unsigned);
  int* reset             = (int*)ws;             ws += 512;

  hipMemsetAsync(bars, 0, 8 * BAR_STRIDE * sizeof(unsigned), stream);
  cvt_bf16<<<1024, 256, 0, stream>>>(W_ih, Wih_bf, (long)G_DIM * D_IN / 4);
  cvt_bf16<<<1024, 256, 0, stream>>>(W_hh, Whh_bf, (long)G_DIM * H_DIM / 4);
  cvt_bf16<<<512, 256, 0, stream>>>(hxs, hbuf, (long)N_B * H_DIM / 4);   // hbuf[0] = bf16(h0)
  reset_kernel<<<128, 512, 0, stream>>>(masks, reset);
  cvt_bf16<<<4096, 256, 0, stream>>>(x, xc_bf, (long)M_ALL * D_IN / 4);

  dim3 gg(G_DIM / 128, M_ALL / 128);   // (24, 512) — one GEMM for all timesteps
  gemm_xp<<<gg, 256, 0, stream>>>(xc_bf, Wih_bf, b_ih, xpT_bf);

  rnn_all<<<256, 256, 0, stream>>>(Whh_bf, xpT_bf, masks, reset, b_hh,
                                   hxs, hbuf, y, hlast, bars);

  ln_kernel<<<T_STEPS * N_B, 256, 0, stream>>>(y, gamma, beta);
}

// Round 17
// 2207.491 us; speedup vs baseline: 1.1497x; 1.0278x over previous
//
#include <hip/hip_runtime.h>

// ---------------- problem constants ----------------
#define T_STEPS 128
#define N_B     512
#define D_IN    1024
#define H_DIM   1024
#define G_DIM   3072        // 3*H
#define M_ALL   (T_STEPS * N_B)   // 65536 rows

typedef short          s8v  __attribute__((ext_vector_type(8)));   // 8 bf16 (4 VGPR)
typedef float          f4v  __attribute__((ext_vector_type(4)));
typedef unsigned short u4v  __attribute__((ext_vector_type(4)));

__device__ __forceinline__ unsigned short f2bf(float f) {
  union { float f; unsigned u; } v; v.f = f;
  unsigned r = v.u + 0x7FFFu + ((v.u >> 16) & 1u);   // RNE
  return (unsigned short)(r >> 16);
}
__device__ __forceinline__ float bf2f(unsigned short h) {
  union { unsigned u; float f; } v; v.u = ((unsigned)h) << 16;
  return v.f;
}
__device__ __forceinline__ void async16(const void* g, void* l) {
  __builtin_amdgcn_global_load_lds(
      (const __attribute__((address_space(1))) unsigned*)g,
      (__attribute__((address_space(3))) unsigned*)l, 16, 0, 0);
}
// sc0|sc1: bypass stale L1/L2, read from the shared Infinity Cache (cross-XCD h)
__device__ __forceinline__ void async16_coh(const void* g, void* l) {
  __builtin_amdgcn_global_load_lds(
      (const __attribute__((address_space(1))) unsigned*)g,
      (__attribute__((address_space(3))) unsigned*)l, 16, 0, 17);
}
// sc0|sc1 coherent bf16 store: write through to the coherence point (cross-XCD h)
__device__ __forceinline__ void store_bf16_coh(unsigned short* p, unsigned short v) {
  unsigned v32 = v;
  asm volatile("global_store_short %0, %1, off sc0 sc1" :: "v"(p), "v"(v32) : "memory");
}
__device__ __forceinline__ float sigmoidf_(float x) { return 1.f / (1.f + __expf(-x)); }
__device__ __forceinline__ float tanhf_(float x)    { return 1.f - 2.f / (1.f + __expf(2.f * x)); }

// ---------------- f32 -> bf16 conversion (vectorized, grid-stride) ----------------
__global__ void cvt_bf16(const float* __restrict__ in, unsigned short* __restrict__ out, long n4) {
  long i = (long)blockIdx.x * blockDim.x + threadIdx.x;
  long stride = (long)gridDim.x * blockDim.x;
  for (; i < n4; i += stride) {
    f4v v = *(const f4v*)(in + i * 4);
    u4v o;
    #pragma unroll
    for (int e = 0; e < 4; ++e) o[e] = f2bf(v[e]);
    *(u4v*)(out + i * 4) = o;
  }
}

// ---------------- reset[t] = (t==0) || any(m[t,:]==1.0) ----------------
__global__ void reset_kernel(const float* __restrict__ masks, int* __restrict__ reset) {
  const int t = blockIdx.x;
  __shared__ int flag;
  if (threadIdx.x == 0) flag = (t == 0) ? 1 : 0;
  __syncthreads();
  if (t > 0 && masks[(size_t)t * N_B + threadIdx.x] == 1.0f) flag = 1;  // benign same-value race
  __syncthreads();
  if (threadIdx.x == 0) reset[t] = flag;
}

// ---------------- xp GEMM (ALL timesteps), TRANSPOSED output + LDS swizzle ----------------
// Proven R11/R13/R14/R16: 0 bank conflicts, ~537us, MfmaUtil 35% (2-phase structural ceiling).
__global__ __launch_bounds__(256) void gemm_xp(const unsigned short* __restrict__ A,
                                               const unsigned short* __restrict__ B,
                                               const float* __restrict__ bias,
                                               unsigned short* __restrict__ C) {
  const int m0 = blockIdx.y * 128, g0 = blockIdx.x * 128;
  const int tid = threadIdx.x, wv = tid >> 6, l = tid & 63;
  const int l15 = l & 15, l4 = l >> 4;
  const int wr = wv >> 1, wc = wv & 1;
  __shared__ unsigned short As[128 * 64], Bs[128 * 64];

  f4v zero4 = {0.f, 0.f, 0.f, 0.f};
  f4v acc[4][4];
  #pragma unroll
  for (int i = 0; i < 4; ++i)
    #pragma unroll
    for (int j = 0; j < 4; ++j) acc[i][j] = zero4;

  const int srow = l >> 3;
  const int selem = ((l & 7) ^ srow) * 8;        // pre-swizzled source col (elements)
  const int swz_rd = (l15 & 7) << 4;             // read-side row-XOR

  for (int kt = 0; kt < 1024; kt += 64) {
    #pragma unroll
    for (int cc = 0; cc < 4; ++cc) {
      int s = wv * 4 + cc;
      int row = s * 8 + srow;
      async16(A + (size_t)(m0 + row) * 1024 + kt + selem, &As[s * 512]);
      async16(B + (size_t)(g0 + row) * 1024 + kt + selem, &Bs[s * 512]);
    }
    __syncthreads();
    #pragma unroll
    for (int ks = 0; ks < 2; ++ks) {
      s8v a[4], b[4];
      #pragma unroll
      for (int i = 0; i < 4; ++i) {
        int ra = wr * 64 + i * 16 + l15, rb = wc * 64 + i * 16 + l15;
        int cb = (ks * 64 + l4 * 16) ^ swz_rd;
        a[i] = *(const s8v*)((const char*)As + ra * 128 + cb);
        b[i] = *(const s8v*)((const char*)Bs + rb * 128 + cb);
      }
      #pragma unroll
      for (int i = 0; i < 4; ++i)
        #pragma unroll
        for (int j = 0; j < 4; ++j)
          acc[i][j] = __builtin_amdgcn_mfma_f32_16x16x32_bf16(a[i], b[j], acc[i][j], 0, 0, 0);
    }
    __syncthreads();
  }
  #pragma unroll
  for (int j = 0; j < 4; ++j) {
    int gcol = g0 + wc * 64 + j * 16 + l15;
    float bv = bias[gcol];
    #pragma unroll
    for (int i = 0; i < 4; ++i) {
      int mrow = m0 + wr * 64 + i * 16 + l4 * 4;
      u4v o;
      #pragma unroll
      for (int r = 0; r < 4; ++r) o[r] = f2bf(acc[i][j][r] + bv);
      *(u4v*)(C + (size_t)gcol * M_ALL + mrow) = o;    // transposed, 8B vector store
    }
  }
}

// ---------------- persistent GRU, v9: R16 + BROADCAST barrier (store+poll, no RMW) ----------------
// Identical to R16's rnn_all except the nt-group barrier: instead of 32 serialized fetch_adds
// on one counter, each block STOREs its own padded flag (fire-and-forget, after vmcnt drain);
// the jt==0 leader's wave-0 polls all 32 flags IN PARALLEL (ballot-reduced, one load latency
// per round) and broadcasts a go-word; followers poll go. Removes RMW serialization at the
// coherence point. Ordering: h-stores are sc0|sc1 + vmcnt-drained before the flag store issues
// -> completed before flag observable; readers re-fetch h with sc0|sc1 loads (proven R8-R16).
__global__ __launch_bounds__(256, 1) void rnn_all(
    const unsigned short* __restrict__ Whh,   // [3072][1024] bf16
    const unsigned short* __restrict__ xpT,   // [3072][65536] bf16 (+b_ih), transposed
    const float* __restrict__ masks,          // [T*N]
    const int* __restrict__ reset,            // [T]
    const float* __restrict__ bhh,            // [3072]
    const float* __restrict__ hxs,            // [512][1024] initial h (f32)
    unsigned short* hbuf,                     // [2][512][1024] bf16 state
    float* __restrict__ y,                    // [T*N][1024] (d_out)
    float* __restrict__ hlast,                // [512][1024]  (d_out tail)
    unsigned* flags,                          // [8][32] flags, each padded to 64B (16 u32)
    unsigned* go) {                           // [8] go words, each padded to 64B
  const int bid = blockIdx.x;
  const int jt = bid & 31, nt = bid >> 5;
  const int j0 = jt * 32, n0 = nt * 64;
  const int tid = threadIdx.x, w = tid >> 6, l = tid & 63;
  const int l15 = l & 15, l4 = l >> 4;
  const int wn = w & 1, wj = w >> 1;          // wave -> (n-half of 32, j-half of 16)
  const size_t NH = (size_t)N_B * H_DIM;

  __shared__ unsigned short Hs[3][64 * 128];  // 48 KB (h slab, swizzled)
  __shared__ unsigned short Ws[3][96 * 128];  // 72 KB (W slab, swizzled)
  __shared__ unsigned short xpl[3][32][64];   // 12 KB xp gate operands (swizzled cols)

  const int lrow4 = l >> 4;                   // staging: lane -> row-within-4
  const int lcb = (l & 15) * 16;              // staging: lane -> 16B col slot
  const int swz_rd = (l15 & 7) << 4;          // read-side row-XOR

  const int jj = j0 + wj * 16 + l15;
  const float br = bhh[jj];
  const float bz = bhh[H_DIM + jj];
  const float bn = bhh[2 * H_DIM + jj];

  // h_prev f32 in registers, carried across ALL 128 steps
  float hreg[2][4];
  #pragma unroll
  for (int i = 0; i < 2; ++i)
    #pragma unroll
    for (int r = 0; r < 4; ++r)
      hreg[i][r] = hxs[(size_t)(n0 + wn * 32 + i * 16 + l4 * 4 + r) * H_DIM + jj];

  f4v zero4 = {0.f, 0.f, 0.f, 0.f};
  s8v zer8 = {0, 0, 0, 0, 0, 0, 0, 0};

  auto stageH = [&](const unsigned short* hread, int buf, int kt) {  // 4 VMEM/wave
    #pragma unroll
    for (int q = 0; q < 4; ++q) {
      int rb = w * 16 + q * 4;
      int row = rb + lrow4;                                   // 0..63
      int cb = lcb ^ ((row & 7) << 4);                        // byte in 256B row
      async16_coh(hread + (size_t)(n0 + row) * H_DIM + kt * 128 + (cb >> 1),
                  &Hs[buf][rb * 128]);
    }
  };
  auto stageW = [&](int buf, int kt) {                        // 6 VMEM/wave
    #pragma unroll
    for (int q = 0; q < 6; ++q) {
      int rb = w * 24 + q * 4;
      int row = rb + lrow4;                                   // 0..95
      int gate = row >> 5, jjl = row & 31;
      int cb = lcb ^ ((row & 7) << 4);
      async16(Whh + ((size_t)gate * H_DIM + j0 + jjl) * H_DIM + kt * 128 + (cb >> 1),
              &Ws[buf][rb * 128]);
    }
  };
  auto stageXP = [&](int t) {                                 // 3 VMEM/wave
    const int jl = w * 8 + (l >> 3);
    const int nelem = ((l & 7) ^ (l >> 3)) * 8;               // pre-swizzled n-offset
    #pragma unroll
    for (int g3 = 0; g3 < 3; ++g3)
      async16(xpT + (size_t)(g3 * H_DIM + j0 + jl) * M_ALL + (size_t)t * N_B + n0 + nelem,
              &xpl[g3][w * 8][0]);
  };

  // ---- priming for t=0 ----
  int rst = reset[0];
  bool zo[2];
  float mreg[2][4];
  #pragma unroll
  for (int i = 0; i < 2; ++i) {
    float mv = masks[(size_t)0 * N_B + n0 + wn * 32 + i * 16 + l15];
    zo[i] = rst && (mv == 0.0f);
  }
  #pragma unroll
  for (int i = 0; i < 2; ++i)
    #pragma unroll
    for (int r = 0; r < 4; ++r)
      mreg[i][r] = masks[(size_t)0 * N_B + n0 + wn * 32 + i * 16 + l4 * 4 + r];
  stageW(0, 0); stageW(1, 1); stageW(2, 2);
  stageXP(0);

  for (int t = 0; t < T_STEPS; ++t) {
    const unsigned short* hread = hbuf + (size_t)(t & 1) * NH;
    unsigned short* hwrite = hbuf + (size_t)((t & 1) ^ 1) * NH;

    stageH(hread, 0, 0); stageH(hread, 1, 1); stageH(hread, 2, 2);

    f4v acc[2][3];
    #pragma unroll
    for (int i = 0; i < 2; ++i)
      #pragma unroll
      for (int g3 = 0; g3 < 3; ++g3) acc[i][g3] = zero4;

#define KT_BODY(KT, VM, DO_STAGE)                                              \
    {                                                                          \
      asm volatile("s_waitcnt vmcnt(" #VM ")" ::: "memory");                   \
      __builtin_amdgcn_s_barrier();                                            \
      __builtin_amdgcn_sched_barrier(0);                                       \
      if (DO_STAGE) { stageH(hread, (KT + 2) % 3, KT + 2); stageW((KT + 2) % 3, KT + 2); } \
      const char* hb = (const char*)&Hs[KT % 3][0];                            \
      const char* wb = (const char*)&Ws[KT % 3][0];                            \
      _Pragma("unroll")                                                        \
      for (int ks = 0; ks < 4; ++ks) {                                         \
        const int kbb = (ks * 64 + l4 * 16) ^ swz_rd;                          \
        s8v a[2], b[3];                                                        \
        _Pragma("unroll")                                                      \
        for (int i = 0; i < 2; ++i) {                                          \
          a[i] = *(const s8v*)(hb + (wn * 32 + i * 16 + l15) * 256 + kbb);     \
          if (zo[i]) a[i] = zer8;                                              \
        }                                                                      \
        _Pragma("unroll")                                                      \
        for (int g3 = 0; g3 < 3; ++g3)                                         \
          b[g3] = *(const s8v*)(wb + (g3 * 32 + wj * 16 + l15) * 256 + kbb);   \
        _Pragma("unroll")                                                      \
        for (int i = 0; i < 2; ++i)                                            \
          _Pragma("unroll")                                                    \
          for (int g3 = 0; g3 < 3; ++g3)                                       \
            acc[i][g3] = __builtin_amdgcn_mfma_f32_16x16x32_bf16(a[i], b[g3],  \
                                                                acc[i][g3], 0, 0, 0); \
      }                                                                        \
    }

    KT_BODY(0, 8,  false)
    KT_BODY(1, 4,  true)
    KT_BODY(2, 10, true)
    KT_BODY(3, 10, true)
    KT_BODY(4, 10, true)
    KT_BODY(5, 10, true)
    KT_BODY(6, 10, false)
    KT_BODY(7, 0,  false)
#undef KT_BODY

    #pragma unroll
    for (int i = 0; i < 2; ++i) {
      #pragma unroll
      for (int r = 0; r < 4; ++r) {
        const int n = n0 + wn * 32 + i * 16 + l4 * 4 + r;
        const int nl = wn * 32 + i * 16 + l4 * 4 + r;           // n-local 0..63
        const int jl = wj * 16 + l15;                           // j-local 0..31
        float hprev = hreg[i][r];
        if (rst && mreg[i][r] == 0.0f) hprev = 0.0f;
        const float hr = acc[i][0][r] + br;
        const float hz = acc[i][1][r] + bz;
        const float hn = acc[i][2][r] + bn;
        const char* xb = (const char*)&xpl[0][0][0];
        const int nb = (nl * 2) ^ ((jl & 7) << 4);              // swizzled byte in 128B col
        const float xr = bf2f(*(const unsigned short*)(xb + 0 * 4096 + jl * 128 + nb));
        const float xz = bf2f(*(const unsigned short*)(xb + 1 * 4096 + jl * 128 + nb));
        const float xn = bf2f(*(const unsigned short*)(xb + 2 * 4096 + jl * 128 + nb));
        const float rg = sigmoidf_(xr + hr);
        const float zg = sigmoidf_(xz + hz);
        const float ng = tanhf_(xn + rg * hn);
        const float hnew = (1.f - zg) * ng + zg * hprev;
        hreg[i][r] = hnew;
        const size_t gidx = (size_t)n * H_DIM + jj;
        y[(size_t)t * NH + gidx] = hnew;
        store_bf16_coh(hwrite + gidx, f2bf(hnew));
        if (t == T_STEPS - 1) hlast[gidx] = hnew;
      }
    }

    __syncthreads();                            // drains vmcnt(0): h stores visible

    // ---- arrival: fire-and-forget flag store (no RMW) ----
    if (tid == 0)
      __hip_atomic_store(&flags[(nt * 32 + jt) * 16], (unsigned)(t + 1),
                         __ATOMIC_RELAXED, __HIP_MEMORY_SCOPE_AGENT);

    // ---- h-independent prestage for t+1 overlaps the barrier wait ----
    int rstN = 0;
    bool zoN[2] = {false, false};
    float mregN[2][4];
    if (t + 1 < T_STEPS) {
      rstN = reset[t + 1];
      #pragma unroll
      for (int i = 0; i < 2; ++i) {
        float mv = masks[(size_t)(t + 1) * N_B + n0 + wn * 32 + i * 16 + l15];
        zoN[i] = rstN && (mv == 0.0f);
      }
      #pragma unroll
      for (int i = 0; i < 2; ++i)
        #pragma unroll
        for (int r = 0; r < 4; ++r)
          mregN[i][r] = masks[(size_t)(t + 1) * N_B + n0 + wn * 32 + i * 16 + l4 * 4 + r];
      stageW(0, 0); stageW(1, 1); stageW(2, 2);
      stageXP(t + 1);
    }

    // ---- broadcast barrier: leader polls 32 flags in parallel, then broadcasts go ----
    if (jt == 0) {
      if (w == 0) {                             // wave 0: lanes poll (l&31)'s flag
        const unsigned* fp = &flags[(nt * 32 + (l & 31)) * 16];
        for (;;) {
          unsigned v = __hip_atomic_load(fp, __ATOMIC_RELAXED, __HIP_MEMORY_SCOPE_AGENT);
          if (__all(v >= (unsigned)(t + 1))) break;
          __builtin_amdgcn_s_sleep(1);
        }
        if (l == 0)
          __hip_atomic_store(&go[nt * 16], (unsigned)(t + 1),
                             __ATOMIC_RELAXED, __HIP_MEMORY_SCOPE_AGENT);
      }
    } else {
      if (tid == 0) {
        while (__hip_atomic_load(&go[nt * 16], __ATOMIC_RELAXED,
                                 __HIP_MEMORY_SCOPE_AGENT) < (unsigned)(t + 1))
          __builtin_amdgcn_s_sleep(1);
      }
    }
    __builtin_amdgcn_s_barrier();               // raw: prestage loads stay in flight
    __builtin_amdgcn_sched_barrier(0);

    rst = rstN;
    #pragma unroll
    for (int i = 0; i < 2; ++i) {
      zo[i] = zoN[i];
      #pragma unroll
      for (int r = 0; r < 4; ++r) mreg[i][r] = mregN[i][r];
    }
  }
}

// ---------------- final LayerNorm over y rows (in place) ----------------
__global__ __launch_bounds__(256) void ln_kernel(float* __restrict__ y,
                                                 const float* __restrict__ gamma,
                                                 const float* __restrict__ beta) {
  const size_t row = blockIdx.x;
  float* p = y + row * (size_t)H_DIM;
  const int tid = threadIdx.x;
  f4v v = *(const f4v*)(p + tid * 4);
  float s = v[0] + v[1] + v[2] + v[3];
  float q = v[0] * v[0] + v[1] * v[1] + v[2] * v[2] + v[3] * v[3];
  #pragma unroll
  for (int off = 32; off > 0; off >>= 1) {
    s += __shfl_down(s, off);
    q += __shfl_down(q, off);
  }
  __shared__ float sb[8];
  const int wid = tid >> 6, lid = tid & 63;
  if (lid == 0) { sb[wid] = s; sb[4 + wid] = q; }
  __syncthreads();
  float S = sb[0] + sb[1] + sb[2] + sb[3];
  float Q = sb[4] + sb[5] + sb[6] + sb[7];
  float mean = S * (1.f / H_DIM);
  float var = Q * (1.f / H_DIM) - mean * mean;
  float inv = rsqrtf(var + 1e-5f);
  f4v g4 = *(const f4v*)(gamma + tid * 4);
  f4v b4 = *(const f4v*)(beta + tid * 4);
  f4v o;
  #pragma unroll
  for (int e = 0; e < 4; ++e) o[e] = (v[e] - mean) * inv * g4[e] + b4[e];
  *(f4v*)(p + tid * 4) = o;
}

// ---------------- host ----------------
extern "C" void kernel_launch(void* const* d_in, const int* in_sizes, int n_in,
                              void* d_out, int out_size, void* d_ws, size_t ws_size,
                              hipStream_t stream) {
  const float* x     = (const float*)d_in[0];
  const float* hxs   = (const float*)d_in[1];
  const float* masks = (const float*)d_in[2];
  const float* W_ih  = (const float*)d_in[3];
  const float* W_hh  = (const float*)d_in[4];
  const float* b_ih  = (const float*)d_in[5];
  const float* b_hh  = (const float*)d_in[6];
  const float* gamma = (const float*)d_in[7];
  const float* beta  = (const float*)d_in[8];
  float* y = (float*)d_out;                                 // [65536][1024]
  float* hlast = y + (size_t)T_STEPS * N_B * H_DIM;         // [512][1024]

  char* ws = (char*)d_ws;
  unsigned short* Wih_bf = (unsigned short*)ws;  ws += (size_t)G_DIM * D_IN * 2;       // 6.3 MB
  unsigned short* Whh_bf = (unsigned short*)ws;  ws += (size_t)G_DIM * H_DIM * 2;      // 6.3 MB
  unsigned short* xc_bf  = (unsigned short*)ws;  ws += (size_t)M_ALL * D_IN * 2;       // 134 MB
  unsigned short* xpT_bf = (unsigned short*)ws;  ws += (size_t)G_DIM * M_ALL * 2;      // 403 MB
  unsigned short* hbuf   = (unsigned short*)ws;  ws += (size_t)2 * N_B * H_DIM * 2;    // 2.1 MB
  unsigned* flags        = (unsigned*)ws;        ws += 8 * 32 * 16 * sizeof(unsigned); // 16 KB
  unsigned* go           = (unsigned*)ws;        ws += 8 * 16 * sizeof(unsigned);      // 512 B
  int* reset             = (int*)ws;             ws += 512;

  hipMemsetAsync(flags, 0, (8 * 32 * 16 + 8 * 16) * sizeof(unsigned), stream);
  cvt_bf16<<<1024, 256, 0, stream>>>(W_ih, Wih_bf, (long)G_DIM * D_IN / 4);
  cvt_bf16<<<1024, 256, 0, stream>>>(W_hh, Whh_bf, (long)G_DIM * H_DIM / 4);
  cvt_bf16<<<512, 256, 0, stream>>>(hxs, hbuf, (long)N_B * H_DIM / 4);   // hbuf[0] = bf16(h0)
  reset_kernel<<<128, 512, 0, stream>>>(masks, reset);
  cvt_bf16<<<4096, 256, 0, stream>>>(x, xc_bf, (long)M_ALL * D_IN / 4);

  dim3 gg(G_DIM / 128, M_ALL / 128);   // (24, 512) — one GEMM for all timesteps
  gemm_xp<<<gg, 256, 0, stream>>>(xc_bf, Wih_bf, b_ih, xpT_bf);

  rnn_all<<<256, 256, 0, stream>>>(Whh_bf, xpT_bf, masks, reset, b_hh,
                                   hxs, hbuf, y, hlast, flags, go);

  ln_kernel<<<T_STEPS * N_B, 256, 0, stream>>>(y, gamma, beta);
}